// Round 10
// baseline (8114.306 us; speedup 1.0000x reference)
//
#include <hip/hip_runtime.h>
#include <stdint.h>

#define T_LEN 4096
#define E_DIM 256
#define HH 256

typedef unsigned long long u64;

__device__ __forceinline__ float sigmoidf_(float x) {
    return __builtin_amdgcn_rcpf(1.0f + __expf(-x));
}
__device__ __forceinline__ float tanh_fast(float x) {
    float e = __expf(2.0f * x);
    return 1.0f - 2.0f * __builtin_amdgcn_rcpf(e + 1.0f);
}

// ---------------------------------------------------------------------------
// Kernel 1: embedding gather fused with input projection (unchanged).
// ---------------------------------------------------------------------------
__global__ __launch_bounds__(256) void proj_kernel(
    const int* __restrict__ sent, const float* __restrict__ embed,
    const float* __restrict__ Wih_f, const float* __restrict__ bih_f, const float* __restrict__ bhh_f,
    const float* __restrict__ Wih_b, const float* __restrict__ bih_b, const float* __restrict__ bhh_b,
    float* __restrict__ gates_f, float* __restrict__ gates_b)
{
    __shared__ float4 xt[16][64];
    const int tid = threadIdx.x;
    const int dir = blockIdx.y;
    const int t0  = blockIdx.x * 16;

    const float* Wih = dir ? Wih_b : Wih_f;
    const float* bih = dir ? bih_b : bih_f;
    const float* bhh = dir ? bhh_b : bhh_f;
    float* gates     = dir ? gates_b : gates_f;

    {
        int row = tid >> 4;
        int c   = tid & 15;
        const float4* src = (const float4*)(embed + (size_t)sent[t0 + row] * E_DIM);
        xt[row][c]      = src[c];
        xt[row][c + 16] = src[c + 16];
        xt[row][c + 32] = src[c + 32];
        xt[row][c + 48] = src[c + 48];
    }
    __syncthreads();

    float acc[4][16];
    #pragma unroll
    for (int ri = 0; ri < 4; ++ri)
        #pragma unroll
        for (int tt = 0; tt < 16; ++tt) acc[ri][tt] = 0.f;

    const float4* wrow0 = (const float4*)(Wih + (size_t)(0 * 256 + tid) * 256);
    const float4* wrow1 = (const float4*)(Wih + (size_t)(1 * 256 + tid) * 256);
    const float4* wrow2 = (const float4*)(Wih + (size_t)(2 * 256 + tid) * 256);
    const float4* wrow3 = (const float4*)(Wih + (size_t)(3 * 256 + tid) * 256);

    for (int k4 = 0; k4 < 64; ++k4) {
        float4 xv[16];
        #pragma unroll
        for (int tt = 0; tt < 16; ++tt) xv[tt] = xt[tt][k4];
        float4 w0 = wrow0[k4], w1 = wrow1[k4], w2 = wrow2[k4], w3 = wrow3[k4];
        #pragma unroll
        for (int tt = 0; tt < 16; ++tt) {
            acc[0][tt] += w0.x*xv[tt].x + w0.y*xv[tt].y + w0.z*xv[tt].z + w0.w*xv[tt].w;
            acc[1][tt] += w1.x*xv[tt].x + w1.y*xv[tt].y + w1.z*xv[tt].z + w1.w*xv[tt].w;
            acc[2][tt] += w2.x*xv[tt].x + w2.y*xv[tt].y + w2.z*xv[tt].z + w2.w*xv[tt].w;
            acc[3][tt] += w3.x*xv[tt].x + w3.y*xv[tt].y + w3.z*xv[tt].z + w3.w*xv[tt].w;
        }
    }

    #pragma unroll
    for (int ri = 0; ri < 4; ++ri) {
        int r = ri * 256 + tid;
        float b = bih[r] + bhh[r];
        #pragma unroll
        for (int tt = 0; tt < 16; ++tt)
            gates[(size_t)(t0 + tt) * 1024 + r] = acc[ri][tt] + b;
    }
}

// ---------------------------------------------------------------------------
// Kernel 2: BiLSTM recurrence — EXACT R5 structure (best measured: 5003us)
// with a DUAL-PATH mailbox replacing the single agent-scope one:
//   fast path : volatile u64 store/load (L1-bypass, served by L2). If the
//               %8->XCD round-robin holds, all 4 blocks of a direction sit
//               on ONE XCD and meet in its coherent L2 (~200-400cy RTT vs
//               ~1500+ at the device/L3 coherence point that AGENT scope
//               requires on this 8-XCD part).
//   agent path: R5's __hip_atomic AGENT mailbox — placement-independent
//               correctness backstop, polled in the same spin loop.
// Producer publishes to BOTH; consumer accepts whichever shows the tag.
// R9 lesson: no slot padding, no sleep backoff (both regressed).
// R6/R7/R8 lesson: one direction per block, 4-way gather, fan-out-1 polls.
// ---------------------------------------------------------------------------
__global__ __launch_bounds__(512, 1) void lstm_kernel(
    const float* __restrict__ Whh_f, const float* __restrict__ Whh_b,
    const float* __restrict__ gates_f, const float* __restrict__ gates_b,
    const float* __restrict__ h0, const float* __restrict__ c0,
    float* __restrict__ h_out, u64* __restrict__ msg, u64* __restrict__ msgF)
{
    const int xcd  = blockIdx.x & 7;
    const int slot = blockIdx.x >> 3;
    if (xcd > 1 || slot > 3) return;   // filler blocks exit
    const int dir = xcd;               // dir-0 blocks: idx 0,8,16,24 -> XCD0
    const int g   = slot;              // dir-1 blocks: idx 1,9,17,25 -> XCD1

    const int tid = threadIdx.x;
    const int s   = tid & 7;           // k-slice 0..7 (32 k each)
    const int jl  = tid >> 3;          // 0..63
    const int j   = g * 64 + jl;       // hidden index 0..255

    const float* Whh   = dir ? Whh_b : Whh_f;
    const float* gates = dir ? gates_b : gates_f;

    // w[gg*32 + i*4 + c] = Whh[(gg*256+j)*256 + s*32 + ((i+s)&7)*4 + c]
    float w[128];
    #pragma unroll
    for (int gg = 0; gg < 4; ++gg) {
        const float4* row = (const float4*)(Whh + (size_t)(gg * 256 + j) * 256 + s * 32);
        #pragma unroll
        for (int i = 0; i < 8; ++i) {
            float4 v = row[(i + s) & 7];
            w[gg * 32 + i * 4 + 0] = v.x;
            w[gg * 32 + i * 4 + 1] = v.y;
            w[gg * 32 + i * 4 + 2] = v.z;
            w[gg * 32 + i * 4 + 3] = v.w;
        }
    }
    #pragma unroll
    for (int k = 0; k < 128; ++k)
        asm volatile("" : "+v"(w[k]));

    __shared__ __align__(16) float h_lds[2][256];

    float c = 0.f;
    if (tid < 64) {
        int j0 = g * 64 + tid;
        float h = h0[dir * HH + j0];
        h_lds[0][j0] = h;
        u64 p = ((u64)1u << 32) | (u64)__float_as_uint(h);
        int idx = (0 * 2 + dir) * 256 + j0;
        *(volatile u64*)&msgF[idx] = p;
        __hip_atomic_store(&msg[idx], p,
                           __ATOMIC_RELAXED, __HIP_MEMORY_SCOPE_AGENT);
    }
    if (s == 0) c = c0[dir * HH + j];

    for (int t = 0; t < T_LEN; ++t) {
        const int tf = dir ? (T_LEN - 1 - t) : t;

        // finalists prefetch gate inputs (overlaps the poll)
        float gin0 = 0.f, gin1 = 0.f, gin2 = 0.f, gin3 = 0.f;
        if (s == 0) {
            const float* gp = gates + (size_t)tf * 1024 + j;
            gin0 = gp[0]; gin1 = gp[256]; gin2 = gp[512]; gin3 = gp[768];
        }

        // poll the 192 remote h values, fan-out 1, into LDS.
        // Dual-path spin: L2 fast line first, agent line as backstop.
        if (tid < 256 && (tid >> 6) != g) {
            const int idx = ((t & 1) * 2 + dir) * 256 + tid;
            volatile u64* fp = (volatile u64*)&msgF[idx];
            u64* ap = &msg[idx];
            const unsigned want = (unsigned)(t + 1);
            u64 m;
            for (;;) {
                m = *fp;                                   // XCD-L2 probe
                if ((unsigned)(m >> 32) == want) break;
                m = __hip_atomic_load(ap, __ATOMIC_RELAXED,
                                      __HIP_MEMORY_SCOPE_AGENT);  // device probe
                if ((unsigned)(m >> 32) == want) break;
            }
            h_lds[t & 1][tid] = __uint_as_float((unsigned)m);
        }
        __syncthreads();   // the ONLY barrier per step

        // 4-gate partial dot over this thread's 32-k slice
        float p0 = 0.f, p1 = 0.f, p2 = 0.f, p3 = 0.f;
        const float4* hp = (const float4*)(&h_lds[t & 1][s * 32]);
        #pragma unroll
        for (int i = 0; i < 8; ++i) {
            float4 h4 = hp[(i + s) & 7];
            p0 += w[i*4+0]*h4.x + w[i*4+1]*h4.y + w[i*4+2]*h4.z + w[i*4+3]*h4.w;
            p1 += w[32+i*4+0]*h4.x + w[32+i*4+1]*h4.y + w[32+i*4+2]*h4.z + w[32+i*4+3]*h4.w;
            p2 += w[64+i*4+0]*h4.x + w[64+i*4+1]*h4.y + w[64+i*4+2]*h4.z + w[64+i*4+3]*h4.w;
            p3 += w[96+i*4+0]*h4.x + w[96+i*4+1]*h4.y + w[96+i*4+2]*h4.z + w[96+i*4+3]*h4.w;
        }

        // butterfly reduce across the 8 k-slices (lane bits 0..2)
        #pragma unroll
        for (int m = 1; m <= 4; m <<= 1) {
            p0 += __shfl_xor(p0, m);
            p1 += __shfl_xor(p1, m);
            p2 += __shfl_xor(p2, m);
            p3 += __shfl_xor(p3, m);
        }

        if (s == 0) {
            float iv = sigmoidf_(gin0 + p0);
            float fv = sigmoidf_(gin1 + p1);
            float gv = tanh_fast(gin2 + p2);
            float ov = sigmoidf_(gin3 + p3);
            c = fv * c + iv * gv;
            float h = ov * tanh_fast(c);
            // publish: fast L2 line first (short path), then agent backstop,
            // then local LDS, then h_out
            u64 pck = (((u64)(unsigned)(t + 2)) << 32) | (u64)__float_as_uint(h);
            const int pidx = (((t + 1) & 1) * 2 + dir) * 256 + j;
            *(volatile u64*)&msgF[pidx] = pck;
            __hip_atomic_store(&msg[pidx], pck,
                               __ATOMIC_RELAXED, __HIP_MEMORY_SCOPE_AGENT);
            h_lds[(t + 1) & 1][j] = h;
            h_out[(size_t)tf * 512 + dir * HH + j] = h;
        }
        // ABA-safe (both paths share the tag discipline): tag t+2 overwrites
        // a slot only after this block's poll saw tag t+1 from every remote
        // block, which sits behind their consumption of tag t + a barrier.
    }
}

// ---------------------------------------------------------------------------
// Kernel 3: feats[t][k] = dot(h_out[t,:], W_out[k,:]) + b_out[k]
// ---------------------------------------------------------------------------
__global__ __launch_bounds__(64) void feats_kernel(
    const float* __restrict__ h_out, const float* __restrict__ W_out,
    const float* __restrict__ b_out, float* __restrict__ feats)
{
    const int t = blockIdx.x;
    const int lane = threadIdx.x;
    const int k = lane >> 1, half = lane & 1;
    const float4* hv = (const float4*)(h_out + (size_t)t * 512 + half * 256);
    const float4* wv = (const float4*)(W_out + (size_t)k * 512 + half * 256);
    float p = 0.f;
    #pragma unroll 16
    for (int i = 0; i < 64; ++i) {
        float4 a = hv[i], b = wv[i];
        p += a.x*b.x + a.y*b.y + a.z*b.z + a.w*b.w;
    }
    p += __shfl_xor(p, 1);
    if (half == 0) feats[t * 32 + k] = p + b_out[k];
}

// ---------------------------------------------------------------------------
// Kernel 4: Viterbi (R4 version — proven).
// ---------------------------------------------------------------------------
#define VT_CHUNK 128
__global__ __launch_bounds__(64) void viterbi_kernel(
    const float* __restrict__ feats, const float* __restrict__ trans,
    float* __restrict__ out)
{
    extern __shared__ unsigned char dynls[];
    unsigned char* ixs = dynls;                       // (T-1)*32 = 131040 B
    float* fchunk = (float*)(dynls + 131072);         // VT_CHUNK*32 floats
    __shared__ float fin[32];

    const int lane = threadIdx.x;
    const int j = lane >> 1, ih = lane & 1;

    float ttr[16];
    #pragma unroll
    for (int q = 0; q < 16; ++q) ttr[q] = trans[(ih * 16 + q) * 32 + j];

    float alpha = 0.f;

    for (int cs = 0; cs < T_LEN; cs += VT_CHUNK) {
        const float4* src = (const float4*)(feats + (size_t)cs * 32);
        float4* dst = (float4*)fchunk;
        #pragma unroll
        for (int i = 0; i < 16; ++i) dst[lane + 64 * i] = src[lane + 64 * i];
        __syncthreads();

        int tbeg = cs;
        if (cs == 0) { alpha = fchunk[j]; tbeg = 1; }

        for (int t = tbeg; t < cs + VT_CHUNK; ++t) {
            float obs = fchunk[(t - cs) * 32 + j];
            float v[16]; int ix[16];
            #pragma unroll
            for (int q = 0; q < 16; ++q) {
                int i = ih * 16 + q;
                v[q] = (__shfl(alpha, 2 * i) + ttr[q]) + obs;
                ix[q] = i;
            }
            #pragma unroll
            for (int st = 8; st >= 1; st >>= 1)
                #pragma unroll
                for (int q = 0; q < 8; ++q)
                    if (q < st && v[q + st] > v[q]) { v[q] = v[q + st]; ix[q] = ix[q + st]; }
            float best = v[0]; int barg = ix[0];

            float ob = __shfl_xor(best, 1); int oa = __shfl_xor(barg, 1);
            float m0 = ih ? ob : best; int a0 = ih ? oa : barg;
            float m1 = ih ? best : ob; int a1 = ih ? barg : oa;
            float m = m0; int a = a0;
            if (m1 > m0) { m = m1; a = a1; }
            if (ih == 0) ixs[(t - 1) * 32 + j] = (unsigned char)a;
            alpha = m;
        }
        __syncthreads();
    }

    if (ih == 0) fin[j] = alpha;
    __syncthreads();

    if (lane == 0) {
        float sc = fin[0]; int cur = 0;
        for (int q = 1; q < 32; ++q)
            if (fin[q] > sc) { sc = fin[q]; cur = q; }
        out[T_LEN] = sc;
        out[T_LEN - 1] = (float)cur;
        for (int t = T_LEN - 2; t >= 0; --t) {
            cur = ixs[t * 32 + cur];
            out[t] = (float)cur;
        }
    }
}

// ---------------------------------------------------------------------------
extern "C" void kernel_launch(void* const* d_in, const int* in_sizes, int n_in,
                              void* d_out, int out_size, void* d_ws, size_t ws_size,
                              hipStream_t stream) {
    const int*   sent  = (const int*)d_in[0];
    const float* embed = (const float*)d_in[1];
    const float* Wih_f = (const float*)d_in[2];
    const float* Whh_f = (const float*)d_in[3];
    const float* bih_f = (const float*)d_in[4];
    const float* bhh_f = (const float*)d_in[5];
    const float* Wih_b = (const float*)d_in[6];
    const float* Whh_b = (const float*)d_in[7];
    const float* bih_b = (const float*)d_in[8];
    const float* bhh_b = (const float*)d_in[9];
    const float* h0    = (const float*)d_in[10];
    const float* c0    = (const float*)d_in[11];
    const float* W_out = (const float*)d_in[12];
    const float* b_out = (const float*)d_in[13];
    const float* trans = (const float*)d_in[14];
    float* out = (float*)d_out;

    float* gates_f = (float*)d_ws;                              // T*1024
    float* gates_b = gates_f + (size_t)T_LEN * 1024;            // T*1024
    float* h_out   = gates_b + (size_t)T_LEN * 1024;            // T*512
    float* feats   = h_out   + (size_t)T_LEN * 512;             // T*32
    u64*   msg     = (u64*)(feats + (size_t)T_LEN * 32);        // 1024 u64 (agent)
    u64*   msgF    = msg + 1024;                                // 1024 u64 (L2 fast)

    dim3 gproj(T_LEN / 16, 2);
    proj_kernel<<<gproj, 256, 0, stream>>>(sent, embed,
        Wih_f, bih_f, bhh_f, Wih_b, bih_b, bhh_b, gates_f, gates_b);

    lstm_kernel<<<64, 512, 0, stream>>>(Whh_f, Whh_b, gates_f, gates_b,
                                        h0, c0, h_out, msg, msgF);

    feats_kernel<<<T_LEN, 64, 0, stream>>>(h_out, W_out, b_out, feats);

    hipFuncSetAttribute((const void*)viterbi_kernel,
                        hipFuncAttributeMaxDynamicSharedMemorySize, 147456);
    viterbi_kernel<<<1, 64, 147456, stream>>>(feats, trans, out);
}